// Round 6
// baseline (184.727 us; speedup 1.0000x reference)
//
#include <hip/hip_runtime.h>

#define KK 8
#define DD 16
#define NN 32
#define TT 200
#define BB 2048
#define NITEMS (BB * TT)          // 409600
#define NBLK_H 1024               // hist/scatter blocks
#define CHUNK (NITEMS / NBLK_H)   // 400 items per hist/scatter block
#define SLOTS 410112              // 64-aligned upper bound: 409600 + 8*63 rounded to 256
#define NBLK_MAIN (SLOTS / 256)   // 1602

// ws layout (bytes)
#define WS_HIST_OFF 0
#define WS_HIST_BYTES (NBLK_H * KK * 4)            // 32 KB
#define WS_SIDX_OFF (WS_HIST_OFF + WS_HIST_BYTES)
#define WS_SIDX_BYTES (SLOTS * 4)                  // 1.64 MB
#define WS_LP_OFF (WS_SIDX_OFF + WS_SIDX_BYTES)
#define WS_LP_BYTES (NITEMS * 4)                   // 1.64 MB
#define WS_NEEDED ((size_t)(WS_LP_OFF + WS_LP_BYTES))

// per-k LDS slab strides (fallback kernel + small tables)
#define SC 516
#define SA 260
#define SE 36
#define SD 20

__device__ __forceinline__ float dot16(const float* __restrict__ row,
                                       const float* __restrict__ z) {
  const float4* r4 = reinterpret_cast<const float4*>(row);
  float4 c0 = r4[0], c1 = r4[1], c2 = r4[2], c3 = r4[3];
  float a = c0.x * z[0], b = c0.y * z[1];
  a = fmaf(c0.z, z[2], a);  b = fmaf(c0.w, z[3], b);
  a = fmaf(c1.x, z[4], a);  b = fmaf(c1.y, z[5], b);
  a = fmaf(c1.z, z[6], a);  b = fmaf(c1.w, z[7], b);
  a = fmaf(c2.x, z[8], a);  b = fmaf(c2.y, z[9], b);
  a = fmaf(c2.z, z[10], a); b = fmaf(c2.w, z[11], b);
  a = fmaf(c3.x, z[12], a); b = fmaf(c3.y, z[13], b);
  a = fmaf(c3.z, z[14], a); b = fmaf(c3.w, z[15], b);
  return a + b;
}

__device__ __forceinline__ void load16(float* __restrict__ d,
                                       const float* __restrict__ s) {
  const float4* p = reinterpret_cast<const float4*>(s);
  float4 a0 = p[0], a1 = p[1], a2 = p[2], a3 = p[3];
  d[0] = a0.x;  d[1] = a0.y;  d[2] = a0.z;  d[3] = a0.w;
  d[4] = a1.x;  d[5] = a1.y;  d[6] = a1.z;  d[7] = a1.w;
  d[8] = a2.x;  d[9] = a2.y;  d[10] = a2.z; d[11] = a2.w;
  d[12] = a3.x; d[13] = a3.y; d[14] = a3.z; d[15] = a3.w;
}

// ---------- K1: per-block histogram over K=8 states ----------
__global__ __launch_bounds__(256) void hist_kernel(const int* __restrict__ dsts,
                                                   int* __restrict__ hist) {
  __shared__ int h[KK];
  const int tid = threadIdx.x;
  if (tid < KK) h[tid] = 0;
  __syncthreads();
  const int base = blockIdx.x * CHUNK;
  for (int ofs = tid; ofs < CHUNK; ofs += 256)
    atomicAdd(&h[dsts[base + ofs]], 1);
  __syncthreads();
  if (tid < KK) hist[blockIdx.x * KK + tid] = h[tid];
}

// ---------- K2: single-block scan; hist[blk][k] -> global base positions.
// Bucket bases are 64-ALIGNED so every wave of the main kernel is single-s;
// pad slots stay -1 (memset) as dummies. ----------
__global__ __launch_bounds__(256) void scan_kernel(int* __restrict__ hist) {
  __shared__ int ht[KK * NBLK_H];     // transposed [k][blk], 32 KB
  __shared__ int partial[KK * 32];
  __shared__ int cnt[KK];
  __shared__ int bbase[KK];
  const int tid = threadIdx.x;
  for (int i = tid; i < KK * NBLK_H; i += 256) {
    int blk = i >> 3, k = i & 7;
    ht[k * NBLK_H + blk] = hist[i];
  }
  __syncthreads();
  const int k = tid >> 5, j = tid & 31;     // 8 buckets x 32 runs of 32 blocks
  {
    int s = 0;
    for (int q = 0; q < 32; ++q) s += ht[k * NBLK_H + j * 32 + q];
    partial[k * 32 + j] = s;
  }
  __syncthreads();
  if (tid < KK) {                           // exclusive scan of the 32 run-sums
    int run = 0;
    for (int j2 = 0; j2 < 32; ++j2) {
      int v = partial[tid * 32 + j2];
      partial[tid * 32 + j2] = run;
      run += v;
    }
    cnt[tid] = run;
  }
  __syncthreads();
  if (tid == 0) {                           // 64-aligned bucket bases
    int cur = 0;
    for (int kk2 = 0; kk2 < KK; ++kk2) {
      bbase[kk2] = cur;
      cur = (cur + cnt[kk2] + 63) & ~63;
    }
  }
  __syncthreads();
  int run = bbase[k] + partial[k * 32 + j]; // rewrite hist with global bases
  for (int q = 0; q < 32; ++q) {
    int blk = j * 32 + q;
    int v = ht[k * NBLK_H + blk];
    hist[blk * KK + k] = run;
    run += v;
  }
}

// ---------- K3: scatter item indices into bucket regions ----------
__global__ __launch_bounds__(256) void scatter_kernel(const int* __restrict__ dsts,
                                                      const int* __restrict__ hist,
                                                      int* __restrict__ sidx) {
  __shared__ int cur[KK];
  const int tid = threadIdx.x;
  if (tid < KK) cur[tid] = hist[blockIdx.x * KK + tid];
  __syncthreads();
  const int base = blockIdx.x * CHUNK;
  for (int ofs = tid; ofs < CHUNK; ofs += 256) {
    int item = base + ofs;
    int pos = atomicAdd(&cur[dsts[item]], 1);   // intra-bucket order free
    sidx[pos] = item;
  }
}

// ---------- K4: main compute. s is WAVE-UNIFORM (sorted + 64-aligned
// buckets) -> C and A rows load from GLOBAL at uniform (scalar) addresses:
// the scalar/SMEM pipe replaces the saturated LDS pipe (216 -> ~25
// ds_read_b128 per wave-batch; the 1 KB/instr LDS->RF return traffic for
// broadcast table reads is gone). Per-item arithmetic is kept in the EXACT
// fold order of round 5 -> per-item lp bitwise identical. ----------
__global__ __launch_bounds__(256) void slds_lp_main(
    const int* __restrict__ sidx,
    const int* __restrict__ dsts,
    const float* __restrict__ zg,
    const float* __restrict__ obsg,
    const float* __restrict__ initlg,
    const float* __restrict__ initloc,
    const float* __restrict__ initls,
    const float* __restrict__ transg,
    const float* __restrict__ Ag,
    const float* __restrict__ dynoff,
    const float* __restrict__ dynls,
    const float* __restrict__ Cg,
    const float* __restrict__ emoff,
    const float* __restrict__ emls,
    float* __restrict__ lpArr)
{
  __shared__ __align__(16) float sEmOff[KK * SE];
  __shared__ __align__(16) float sEmInv[KK * SE];
  __shared__ __align__(16) float sDynOff[KK * SD];
  __shared__ __align__(16) float sDynInv[KK * SD];
  __shared__ float sTrans[KK * KK];
  __shared__ float sEmConst[KK];
  __shared__ float sDynConst[KK];
  __shared__ float sInitLp[KK];

  const float HALF_LOG2PI = 0.91893853320467274178f;
  const int tid = threadIdx.x;

  if (tid < KK * NN) {                              // 256
    int k = tid >> 5, n = tid & 31;
    sEmOff[k * SE + n] = emoff[tid];
    sEmInv[k * SE + n] = expf(-emls[tid]);
  }
  if (tid < KK * DD) {                              // 128
    int k = tid >> 4, d = tid & 15;
    sDynOff[k * SD + d] = dynoff[tid];
    sDynInv[k * SD + d] = 1.0f / dynls[tid];
  }
  if (tid < KK * KK) {                              // 64: trans log-softmax
    int kr = tid >> 3;
    float mx = transg[kr * KK];
    for (int j = 1; j < KK; ++j) mx = fmaxf(mx, transg[kr * KK + j]);
    float ss = 0.f;
    for (int j = 0; j < KK; ++j) ss += expf(transg[kr * KK + j] - mx);
    sTrans[tid] = transg[tid] - (logf(ss) + mx);
  }
  if (tid < KK) {                                   // per-k constants
    int k = tid;
    float se = 0.f;
    for (int n = 0; n < NN; ++n) se -= emls[k * NN + n];
    sEmConst[k] = se - NN * HALF_LOG2PI;
    float sd = 0.f;
    for (int d = 0; d < DD; ++d) sd -= logf(dynls[k * DD + d]);
    sDynConst[k] = sd - DD * HALF_LOG2PI;
    float mx = initlg[0];
    for (int j = 1; j < KK; ++j) mx = fmaxf(mx, initlg[j]);
    float ss = 0.f;
    for (int j = 0; j < KK; ++j) ss += expf(initlg[j] - mx);
    float si = 0.f;
    for (int d = 0; d < DD; ++d) si -= initls[k * DD + d];
    sInitLp[k] = initlg[k] - (logf(ss) + mx) + si - DD * HALF_LOG2PI;
  }
  __syncthreads();

  const int slot = blockIdx.x * 256 + tid;
  int idx = sidx[slot];
  const int idx0 = __builtin_amdgcn_readfirstlane(idx);
  if (idx0 < 0) return;                   // all-dummy tail wave (uniform branch)
  const bool valid = idx >= 0;            // dummies are a suffix of the wave
  const int idxc = valid ? idx : idx0;    // clamp: follow lane 0's (real) item
  // wave-uniform state -> scalar table addressing
  const int su = __builtin_amdgcn_readfirstlane(dsts[idx0]);

  const int t = idxc - (idxc / TT) * TT;

  float z[16];
  load16(z, zg + (size_t)idxc * DD);
  float lp;

  // ---- dynamics / init FIRST (round-5 fold order; zp dies here) ----
  if (t != 0) {
    const int sp = dsts[idxc - 1];
    float zp[16];
    load16(zp, zg + (size_t)(idxc - 1) * DD);
    const float* __restrict__ Ab = Ag + (size_t)su * (DD * DD);  // uniform rows
    const int db4 = su * (SD / 4);
    float a2acc = 0.f;
#pragma unroll
    for (int g = 0; g < 4; ++g) {
      const int i0 = g * 4;
      float4 off = reinterpret_cast<const float4*>(sDynOff)[db4 + g];
      float4 inv = reinterpret_cast<const float4*>(sDynInv)[db4 + g];
      float l0 = dot16(&Ab[(i0 + 0) * DD], zp) + off.x;
      float l1 = dot16(&Ab[(i0 + 1) * DD], zp) + off.y;
      float l2 = dot16(&Ab[(i0 + 2) * DD], zp) + off.z;
      float l3 = dot16(&Ab[(i0 + 3) * DD], zp) + off.w;
      float d0 = (z[i0 + 0] - l0) * inv.x;
      float d1 = (z[i0 + 1] - l1) * inv.y;
      float d2 = (z[i0 + 2] - l2) * inv.z;
      float d3 = (z[i0 + 3] - l3) * inv.w;
      a2acc = fmaf(d0, d0, a2acc); a2acc = fmaf(d1, d1, a2acc);
      a2acc = fmaf(d2, d2, a2acc); a2acc = fmaf(d3, d3, a2acc);
    }
    lp = -0.5f * a2acc + sDynConst[su] + sTrans[sp * KK + su];
  } else {
    const float* __restrict__ ploc = initloc + su * DD;   // uniform rows
    const float* __restrict__ pls  = initls + su * DD;
    float a2acc = 0.f;
#pragma unroll
    for (int g = 0; g < 4; ++g) {
      const int i0 = g * 4;
      float4 loc = reinterpret_cast<const float4*>(ploc)[g];
      float4 ls  = reinterpret_cast<const float4*>(pls)[g];
      float d0 = (z[i0 + 0] - loc.x) * expf(-ls.x);
      float d1 = (z[i0 + 1] - loc.y) * expf(-ls.y);
      float d2 = (z[i0 + 2] - loc.z) * expf(-ls.z);
      float d3 = (z[i0 + 3] - loc.w) * expf(-ls.w);
      a2acc = fmaf(d0, d0, a2acc); a2acc = fmaf(d1, d1, a2acc);
      a2acc = fmaf(d2, d2, a2acc); a2acc = fmaf(d3, d3, a2acc);
    }
    lp = -0.5f * a2acc + sInitLp[su];
  }

  // ---- emissions: C rows from global at uniform (scalar) addresses ----
  {
    const float* __restrict__ Cs = Cg + (size_t)su * (NN * DD);
    const float4* o4 = reinterpret_cast<const float4*>(obsg + (size_t)idxc * NN);
    const int eb4 = su * (SE / 4);
    float acc = 0.f;
#pragma unroll 1
    for (int g = 0; g < 8; ++g) {
      float4 o = o4[g];
      float4 off = reinterpret_cast<const float4*>(sEmOff)[eb4 + g];
      float4 inv = reinterpret_cast<const float4*>(sEmInv)[eb4 + g];
      int n0 = g * 4;
      float l0 = dot16(&Cs[(n0 + 0) * DD], z) + off.x;
      float l1 = dot16(&Cs[(n0 + 1) * DD], z) + off.y;
      float l2 = dot16(&Cs[(n0 + 2) * DD], z) + off.z;
      float l3 = dot16(&Cs[(n0 + 3) * DD], z) + off.w;
      float d0 = (o.x - l0) * inv.x;
      float d1 = (o.y - l1) * inv.y;
      float d2 = (o.z - l2) * inv.z;
      float d3 = (o.w - l3) * inv.w;
      acc = fmaf(d0, d0, acc); acc = fmaf(d1, d1, acc);
      acc = fmaf(d2, d2, acc); acc = fmaf(d3, d3, acc);
    }
    lp += -0.5f * acc + sEmConst[su];
  }

  if (valid) lpArr[idx] = lp;   // unique slot per item, plain store
}

// ---------- K5: natural-order segmented reduction (bitwise-identical to
// the accumulation structure of the previously-passing rounds) ----------
__global__ __launch_bounds__(256) void reduce_kernel(const float* __restrict__ lpArr,
                                                     float* __restrict__ out) {
  const int tid = threadIdx.x;
  const int item = blockIdx.x * 256 + tid;
  const int b = item / TT;
  float v = lpArr[item];
  const int lane = tid & 63;
#pragma unroll
  for (int off = 1; off < 64; off <<= 1) {
    float ov = __shfl_up(v, off, 64);
    int obk = __shfl_up(b, off, 64);
    if (lane >= off && obk == b) v += ov;
  }
  int nb = __shfl_down(b, 1, 64);
  if (lane == 63 || nb != b) atomicAdd(&out[b], v);
}

// ---------- fallback: round-5 single kernel (used only if ws too small) ----------
__global__ __launch_bounds__(512) void slds_lp_kernel(
    const int* __restrict__ dsts, const float* __restrict__ zg,
    const float* __restrict__ obsg, const float* __restrict__ initlg,
    const float* __restrict__ initloc, const float* __restrict__ initls,
    const float* __restrict__ transg, const float* __restrict__ Ag,
    const float* __restrict__ dynoff, const float* __restrict__ dynls,
    const float* __restrict__ Cg, const float* __restrict__ emoff,
    const float* __restrict__ emls, float* __restrict__ out)
{
  __shared__ __align__(16) float sC[KK * SC];
  __shared__ __align__(16) float sA[KK * SA];
  __shared__ __align__(16) float sEmOff[KK * SE];
  __shared__ __align__(16) float sEmInv[KK * SE];
  __shared__ __align__(16) float sDynOff[KK * SD];
  __shared__ __align__(16) float sDynInv[KK * SD];
  __shared__ float sTrans[KK * KK];
  __shared__ float sEmConst[KK];
  __shared__ float sDynConst[KK];
  __shared__ float sInitLp[KK];
  const float HALF_LOG2PI = 0.91893853320467274178f;
  const int tid = threadIdx.x;
  for (int i = tid; i < KK * NN * DD; i += 512) {
    int k = i >> 9, r = i & 511;
    sC[k * SC + r] = Cg[i];
  }
  for (int i = tid; i < KK * DD * DD; i += 512) {
    int k = i >> 8, r = i & 255;
    sA[k * SA + r] = Ag[i];
  }
  if (tid < KK * NN) {
    int k = tid >> 5, n = tid & 31;
    sEmOff[k * SE + n] = emoff[tid];
    sEmInv[k * SE + n] = expf(-emls[tid]);
  }
  if (tid < KK * DD) {
    int k = tid >> 4, d = tid & 15;
    sDynOff[k * SD + d] = dynoff[tid];
    sDynInv[k * SD + d] = 1.0f / dynls[tid];
  }
  if (tid < KK * KK) {
    int kr = tid >> 3;
    float mx = transg[kr * KK];
    for (int j = 1; j < KK; ++j) mx = fmaxf(mx, transg[kr * KK + j]);
    float ss = 0.f;
    for (int j = 0; j < KK; ++j) ss += expf(transg[kr * KK + j] - mx);
    sTrans[tid] = transg[tid] - (logf(ss) + mx);
  }
  if (tid < KK) {
    int k = tid;
    float se = 0.f;
    for (int n = 0; n < NN; ++n) se -= emls[k * NN + n];
    sEmConst[k] = se - NN * HALF_LOG2PI;
    float sd = 0.f;
    for (int d = 0; d < DD; ++d) sd -= logf(dynls[k * DD + d]);
    sDynConst[k] = sd - DD * HALF_LOG2PI;
    float mx = initlg[0];
    for (int j = 1; j < KK; ++j) mx = fmaxf(mx, initlg[j]);
    float ss = 0.f;
    for (int j = 0; j < KK; ++j) ss += expf(initlg[j] - mx);
    float si = 0.f;
    for (int d = 0; d < DD; ++d) si -= initls[k * DD + d];
    sInitLp[k] = initlg[k] - (logf(ss) + mx) + si - DD * HALF_LOG2PI;
  }
  __syncthreads();
  if (tid < 400) {
    const int item = blockIdx.x * 400 + tid;
    const int b = item / TT;
    const int t = item - b * TT;
    float z[16];
    load16(z, zg + (size_t)item * DD);
    const int s = dsts[item];
    float lp;
    if (t != 0) {
      const int sp = dsts[item - 1];
      float zp[16];
      load16(zp, zg + (size_t)(item - 1) * DD);
      const float* __restrict__ Ab = &sA[s * SA];
      const int db4 = s * (SD / 4);
      float a2acc = 0.f;
#pragma unroll
      for (int g = 0; g < 4; ++g) {
        const int i0 = g * 4;
        float4 off = reinterpret_cast<const float4*>(sDynOff)[db4 + g];
        float4 inv = reinterpret_cast<const float4*>(sDynInv)[db4 + g];
        float l0 = dot16(&Ab[(i0 + 0) * DD], zp) + off.x;
        float l1 = dot16(&Ab[(i0 + 1) * DD], zp) + off.y;
        float l2 = dot16(&Ab[(i0 + 2) * DD], zp) + off.z;
        float l3 = dot16(&Ab[(i0 + 3) * DD], zp) + off.w;
        float d0 = (z[i0 + 0] - l0) * inv.x;
        float d1 = (z[i0 + 1] - l1) * inv.y;
        float d2 = (z[i0 + 2] - l2) * inv.z;
        float d3 = (z[i0 + 3] - l3) * inv.w;
        a2acc = fmaf(d0, d0, a2acc); a2acc = fmaf(d1, d1, a2acc);
        a2acc = fmaf(d2, d2, a2acc); a2acc = fmaf(d3, d3, a2acc);
      }
      lp = -0.5f * a2acc + sDynConst[s] + sTrans[sp * KK + s];
    } else {
      const float* __restrict__ ploc = initloc + s * DD;
      const float* __restrict__ pls  = initls + s * DD;
      float a2acc = 0.f;
#pragma unroll
      for (int g = 0; g < 4; ++g) {
        const int i0 = g * 4;
        float4 loc = reinterpret_cast<const float4*>(ploc)[g];
        float4 ls  = reinterpret_cast<const float4*>(pls)[g];
        float d0 = (z[i0 + 0] - loc.x) * expf(-ls.x);
        float d1 = (z[i0 + 1] - loc.y) * expf(-ls.y);
        float d2 = (z[i0 + 2] - loc.z) * expf(-ls.z);
        float d3 = (z[i0 + 3] - loc.w) * expf(-ls.w);
        a2acc = fmaf(d0, d0, a2acc); a2acc = fmaf(d1, d1, a2acc);
        a2acc = fmaf(d2, d2, a2acc); a2acc = fmaf(d3, d3, a2acc);
      }
      lp = -0.5f * a2acc + sInitLp[s];
    }
    {
      const float4* o4 = reinterpret_cast<const float4*>(obsg + (size_t)item * NN);
      const int cb = s * SC;
      const int eb4 = s * (SE / 4);
      float acc = 0.f;
#pragma unroll 1
      for (int g = 0; g < 8; ++g) {
        float4 o = o4[g];
        float4 off = reinterpret_cast<const float4*>(sEmOff)[eb4 + g];
        float4 inv = reinterpret_cast<const float4*>(sEmInv)[eb4 + g];
        int n0 = g * 4;
        float l0 = dot16(&sC[cb + (n0 + 0) * DD], z) + off.x;
        float l1 = dot16(&sC[cb + (n0 + 1) * DD], z) + off.y;
        float l2 = dot16(&sC[cb + (n0 + 2) * DD], z) + off.z;
        float l3 = dot16(&sC[cb + (n0 + 3) * DD], z) + off.w;
        float d0 = (o.x - l0) * inv.x;
        float d1 = (o.y - l1) * inv.y;
        float d2 = (o.z - l2) * inv.z;
        float d3 = (o.w - l3) * inv.w;
        acc = fmaf(d0, d0, acc); acc = fmaf(d1, d1, acc);
        acc = fmaf(d2, d2, acc); acc = fmaf(d3, d3, acc);
      }
      lp += -0.5f * acc + sEmConst[s];
    }
    const int lane = tid & 63;
    float v = lp;
#pragma unroll
    for (int off = 1; off < 64; off <<= 1) {
      float ov = __shfl_up(v, off, 64);
      int obk = __shfl_up(b, off, 64);
      if (lane >= off && obk == b) v += ov;
    }
    int nb = __shfl_down(b, 1, 64);
    if (lane == 63 || tid == 399 || nb != b) atomicAdd(&out[b], v);
  }
}

extern "C" void kernel_launch(void* const* d_in, const int* in_sizes, int n_in,
                              void* d_out, int out_size, void* d_ws, size_t ws_size,
                              hipStream_t stream) {
  const int*   dsts    = (const int*)d_in[0];
  const float* zg      = (const float*)d_in[1];
  const float* obsg    = (const float*)d_in[2];
  const float* initlg  = (const float*)d_in[3];
  const float* initloc = (const float*)d_in[4];
  const float* initls  = (const float*)d_in[5];
  const float* transg  = (const float*)d_in[6];
  const float* Ag      = (const float*)d_in[7];
  const float* dynoff  = (const float*)d_in[8];
  const float* dynls   = (const float*)d_in[9];
  const float* Cg      = (const float*)d_in[10];
  const float* emoff   = (const float*)d_in[11];
  const float* emls    = (const float*)d_in[12];
  float* out = (float*)d_out;

  hipMemsetAsync(d_out, 0, BB * sizeof(float), stream);

  if (d_ws == nullptr || ws_size < WS_NEEDED) {
    // fallback: proven round-5 single kernel
    slds_lp_kernel<<<1024, 512, 0, stream>>>(dsts, zg, obsg, initlg, initloc,
                                             initls, transg, Ag, dynoff, dynls,
                                             Cg, emoff, emls, out);
    return;
  }

  int*   hist  = (int*)((char*)d_ws + WS_HIST_OFF);
  int*   sidx  = (int*)((char*)d_ws + WS_SIDX_OFF);
  float* lpArr = (float*)((char*)d_ws + WS_LP_OFF);

  hipMemsetAsync(sidx, 0xFF, WS_SIDX_BYTES, stream);   // dummies = -1

  hist_kernel<<<NBLK_H, 256, 0, stream>>>(dsts, hist);
  scan_kernel<<<1, 256, 0, stream>>>(hist);
  scatter_kernel<<<NBLK_H, 256, 0, stream>>>(dsts, hist, sidx);
  slds_lp_main<<<NBLK_MAIN, 256, 0, stream>>>(sidx, dsts, zg, obsg, initlg,
                                              initloc, initls, transg, Ag,
                                              dynoff, dynls, Cg, emoff, emls,
                                              lpArr);
  reduce_kernel<<<NITEMS / 256, 256, 0, stream>>>(lpArr, out);
}

// Round 7
// 166.727 us; speedup vs baseline: 1.1080x; 1.1080x over previous
//
#include <hip/hip_runtime.h>

#define KK 8
#define DD 16
#define NN 32
#define TT 200
#define BB 2048

// per-k LDS slab strides, == 4 (mod 32) floats AND multiples of 4 (16-B
// alignment) so the <=8 distinct per-lane k values spread across banks ->
// conflict-free (broadcast) ds_read_b128
#define SCH 260  // C-EVEN-rows slab stride (16 rows x 16 = 256 used)
#define SA  260  // A slab stride (256 used)
#define SE  36   // emission table stride (32 used)
#define SD  20   // dyn table stride (16 used)

// works for LDS or global rows: compiler picks ds_read_b128 vs
// global_load_dwordx4 from pointer provenance
__device__ __forceinline__ float dot16(const float* __restrict__ row,
                                       const float* __restrict__ z) {
  const float4* r4 = reinterpret_cast<const float4*>(row);
  float4 c0 = r4[0], c1 = r4[1], c2 = r4[2], c3 = r4[3];
  float a = c0.x * z[0], b = c0.y * z[1];
  a = fmaf(c0.z, z[2], a);  b = fmaf(c0.w, z[3], b);
  a = fmaf(c1.x, z[4], a);  b = fmaf(c1.y, z[5], b);
  a = fmaf(c1.z, z[6], a);  b = fmaf(c1.w, z[7], b);
  a = fmaf(c2.x, z[8], a);  b = fmaf(c2.y, z[9], b);
  a = fmaf(c2.z, z[10], a); b = fmaf(c2.w, z[11], b);
  a = fmaf(c3.x, z[12], a); b = fmaf(c3.y, z[13], b);
  a = fmaf(c3.z, z[14], a); b = fmaf(c3.w, z[15], b);
  return a + b;
}

// const-indexed register fill (keeps the array SROA-able into VGPRs)
__device__ __forceinline__ void load16(float* __restrict__ d,
                                       const float* __restrict__ s) {
  const float4* p = reinterpret_cast<const float4*>(s);
  float4 a0 = p[0], a1 = p[1], a2 = p[2], a3 = p[3];
  d[0] = a0.x;  d[1] = a0.y;  d[2] = a0.z;  d[3] = a0.w;
  d[4] = a1.x;  d[5] = a1.y;  d[6] = a1.z;  d[7] = a1.w;
  d[8] = a2.x;  d[9] = a2.y;  d[10] = a2.z; d[11] = a2.w;
  d[12] = a3.x; d[13] = a3.y; d[14] = a3.z; d[15] = a3.w;
}

// PIPE LEDGER (round-7 theory): the R5 plateau (44.5us, invariant under
// 16->32 waves/CU) is the LDS RETURN PATH: every ds_read_b128 delivers
// 64 x 16 B = 1 KB to the RF even when broadcast (m134 ~12cyc/instr).
// R5 issued ~216 b128 per 64-item batch -> 216*12*25 batches/CU ~ 27us
// floor. This version splits the C table BY ROW PARITY: even rows stay in
// LDS, odd rows come from global (C = 64 KB, permanently L1/L2-hot), so
// every emission iteration has 2 LDS rows + 2 global rows in flight on
// PARALLEL pipes. LDS instrs/item: 216 -> 152 (floor ~19us). Unlike R4
// (all-of-A global = one long dependent chain, VALUBusy 14%), the
// per-iteration interleave overlaps the global latency with LDS compute.
// R6 lesson: do NOT sort -- scattered z/obs gathers cost more (60us,
// 95 MB fetch) than wave-uniform tables save.
// OCCUPANCY: VGPR 65..128 is one residency class (16 waves/CU, 4 blocks);
// grid 1024 x 400 items = exactly B*T, uniform 4/CU, single round.
__global__ __launch_bounds__(256) void slds_lp_kernel(
    const int* __restrict__ dsts,      // [B,T]
    const float* __restrict__ zg,      // [B,T,D]
    const float* __restrict__ obsg,    // [B,T,N]
    const float* __restrict__ initlg,  // [K]
    const float* __restrict__ initloc, // [K,D]
    const float* __restrict__ initls,  // [K,D]
    const float* __restrict__ transg,  // [K,K]
    const float* __restrict__ Ag,      // [K,D,D]
    const float* __restrict__ dynoff,  // [K,D]
    const float* __restrict__ dynls,   // [K,D] (scale directly, NOT log)
    const float* __restrict__ Cg,      // [K,N,D]
    const float* __restrict__ emoff,   // [K,N]
    const float* __restrict__ emls,    // [K,N]
    float* __restrict__ out)           // [B]
{
  __shared__ __align__(16) float sC[KK * SCH];   // EVEN C rows only
  __shared__ __align__(16) float sA[KK * SA];
  __shared__ __align__(16) float sEmOff[KK * SE];
  __shared__ __align__(16) float sEmInv[KK * SE];
  __shared__ __align__(16) float sDynOff[KK * SD];
  __shared__ __align__(16) float sDynInv[KK * SD];
  __shared__ float sTrans[KK * KK];
  __shared__ float sEmConst[KK];
  __shared__ float sDynConst[KK];
  __shared__ float sInitLp[KK];

  const float HALF_LOG2PI = 0.91893853320467274178f;
  const int tid = threadIdx.x;

  // ---- stage params into LDS (transforms applied once per block) ----
  for (int i = tid; i < KK * (NN / 2) * DD; i += 256) {  // 2048: even rows
    int k = i >> 8, r = i & 255;                          // r = nh*16 + d
    sC[k * SCH + r] = Cg[k * (NN * DD) + (r >> 4) * 32 + (r & 15)];
  }
  for (int i = tid; i < KK * DD * DD; i += 256) {         // 2048
    int k = i >> 8, r = i & 255;
    sA[k * SA + r] = Ag[i];
  }
  if (tid < KK * NN) {                              // 256
    int k = tid >> 5, n = tid & 31;
    sEmOff[k * SE + n] = emoff[tid];
    sEmInv[k * SE + n] = expf(-emls[tid]);
  }
  if (tid < KK * DD) {                              // 128
    int k = tid >> 4, d = tid & 15;
    sDynOff[k * SD + d] = dynoff[tid];
    sDynInv[k * SD + d] = 1.0f / dynls[tid];
  }
  if (tid < KK * KK) {                              // 64: trans log-softmax
    int kr = tid >> 3;
    float mx = transg[kr * KK];
    for (int j = 1; j < KK; ++j) mx = fmaxf(mx, transg[kr * KK + j]);
    float ss = 0.f;
    for (int j = 0; j < KK; ++j) ss += expf(transg[kr * KK + j] - mx);
    sTrans[tid] = transg[tid] - (logf(ss) + mx);
  }
  if (tid < KK) {                                   // per-k constants
    int k = tid;
    float se = 0.f;
    for (int n = 0; n < NN; ++n) se -= emls[k * NN + n];
    sEmConst[k] = se - NN * HALF_LOG2PI;
    float sd = 0.f;
    for (int d = 0; d < DD; ++d) sd -= logf(dynls[k * DD + d]);
    sDynConst[k] = sd - DD * HALF_LOG2PI;
    float mx = initlg[0];
    for (int j = 1; j < KK; ++j) mx = fmaxf(mx, initlg[j]);
    float ss = 0.f;
    for (int j = 0; j < KK; ++j) ss += expf(initlg[j] - mx);
    float si = 0.f;
    for (int d = 0; d < DD; ++d) si -= initls[k * DD + d];
    sInitLp[k] = initlg[k] - (logf(ss) + mx) + si - DD * HALF_LOG2PI;
  }
  __syncthreads();

  // ---- block bk owns items [bk*400, bk*400+400) == exactly 2 batch
  //      elements. Pass 1: all 256 threads; pass 2: tid < 144. ----
  const int base = blockIdx.x * 400;
  for (int ofs = tid; ofs < 400; ofs += 256) {
    const int item = base + ofs;
    const int b = item / TT;
    const int t = item - b * TT;

    float z[16];
    load16(z, zg + (size_t)item * DD);
    const int s = dsts[item];
    float lp;

    // ---- dynamics / init FIRST (zp dies before the emission loop) ----
    if (t != 0) {
      const int sp = dsts[item - 1];
      float zp[16];
      load16(zp, zg + (size_t)(item - 1) * DD);
      const float* __restrict__ Ab = &sA[s * SA];   // LDS broadcast
      const int db4 = s * (SD / 4);
      float a2acc = 0.f;
      // FULL unroll: compile-time indices keep z/zp in VGPRs (rule #20)
#pragma unroll
      for (int g = 0; g < 4; ++g) {
        const int i0 = g * 4;
        float4 off = reinterpret_cast<const float4*>(sDynOff)[db4 + g];
        float4 inv = reinterpret_cast<const float4*>(sDynInv)[db4 + g];
        float l0 = dot16(&Ab[(i0 + 0) * DD], zp) + off.x;
        float l1 = dot16(&Ab[(i0 + 1) * DD], zp) + off.y;
        float l2 = dot16(&Ab[(i0 + 2) * DD], zp) + off.z;
        float l3 = dot16(&Ab[(i0 + 3) * DD], zp) + off.w;
        float d0 = (z[i0 + 0] - l0) * inv.x;
        float d1 = (z[i0 + 1] - l1) * inv.y;
        float d2 = (z[i0 + 2] - l2) * inv.z;
        float d3 = (z[i0 + 3] - l3) * inv.w;
        a2acc = fmaf(d0, d0, a2acc); a2acc = fmaf(d1, d1, a2acc);
        a2acc = fmaf(d2, d2, a2acc); a2acc = fmaf(d3, d3, a2acc);
      }
      lp = -0.5f * a2acc + sDynConst[s] + sTrans[sp * KK + s];
    } else {
      // rare (1/200): init tables from global + per-item expf
      // (same inputs, same formula -> bit-identical to staged version)
      const float* __restrict__ ploc = initloc + s * DD;
      const float* __restrict__ pls  = initls + s * DD;
      float a2acc = 0.f;
#pragma unroll
      for (int g = 0; g < 4; ++g) {
        const int i0 = g * 4;
        float4 loc = reinterpret_cast<const float4*>(ploc)[g];
        float4 ls  = reinterpret_cast<const float4*>(pls)[g];
        float d0 = (z[i0 + 0] - loc.x) * expf(-ls.x);
        float d1 = (z[i0 + 1] - loc.y) * expf(-ls.y);
        float d2 = (z[i0 + 2] - loc.z) * expf(-ls.z);
        float d3 = (z[i0 + 3] - loc.w) * expf(-ls.w);
        a2acc = fmaf(d0, d0, a2acc); a2acc = fmaf(d1, d1, a2acc);
        a2acc = fmaf(d2, d2, a2acc); a2acc = fmaf(d3, d3, a2acc);
      }
      lp = -0.5f * a2acc + sInitLp[s];
    }

    // ---- emissions: per iteration 2 rows from LDS (even n) + 2 rows
    //      from global L1 (odd n) -> both pipes busy every iteration,
    //      global latency covered by LDS-row compute + 16 waves/CU.
    //      acc fold order (rows 4g,4g+1,4g+2,4g+3) identical to R5. ----
    {
      const float4* o4 = reinterpret_cast<const float4*>(obsg + (size_t)item * NN);
      const float* __restrict__ Cob = Cg + (size_t)s * (NN * DD);  // odd rows
      const int cb = s * SCH;
      const int eb4 = s * (SE / 4);
      float acc = 0.f;
#pragma unroll 1
      for (int g = 0; g < 8; ++g) {
        float4 o = o4[g];
        float4 off = reinterpret_cast<const float4*>(sEmOff)[eb4 + g];
        float4 inv = reinterpret_cast<const float4*>(sEmInv)[eb4 + g];
        int n0 = g * 4;
        float l0 = dot16(&sC[cb + (2 * g + 0) * DD], z) + off.x;  // row 4g   (LDS)
        float l1 = dot16(&Cob[(n0 + 1) * DD], z) + off.y;         // row 4g+1 (global)
        float l2 = dot16(&sC[cb + (2 * g + 1) * DD], z) + off.z;  // row 4g+2 (LDS)
        float l3 = dot16(&Cob[(n0 + 3) * DD], z) + off.w;         // row 4g+3 (global)
        float d0 = (o.x - l0) * inv.x;
        float d1 = (o.y - l1) * inv.y;
        float d2 = (o.z - l2) * inv.z;
        float d3 = (o.w - l3) * inv.w;
        acc = fmaf(d0, d0, acc); acc = fmaf(d1, d1, acc);
        acc = fmaf(d2, d2, acc); acc = fmaf(d3, d3, acc);
      }
      lp += -0.5f * acc + sEmConst[s];
    }

    // ---- wave-level segmented sum keyed by b, then atomic.
    //      ofs==399 guards the pass-2 partial wave (next lane inactive
    //      -> garbage nb; force the last active lane's atomic). ----
    const int lane = tid & 63;
    float v = lp;
#pragma unroll
    for (int off = 1; off < 64; off <<= 1) {
      float ov = __shfl_up(v, off, 64);
      int obk = __shfl_up(b, off, 64);
      if (lane >= off && obk == b) v += ov;
    }
    int nb = __shfl_down(b, 1, 64);
    if (lane == 63 || ofs == 399 || nb != b) atomicAdd(&out[b], v);
  }
}

extern "C" void kernel_launch(void* const* d_in, const int* in_sizes, int n_in,
                              void* d_out, int out_size, void* d_ws, size_t ws_size,
                              hipStream_t stream) {
  const int*   dsts    = (const int*)d_in[0];
  const float* zg      = (const float*)d_in[1];
  const float* obsg    = (const float*)d_in[2];
  const float* initlg  = (const float*)d_in[3];
  const float* initloc = (const float*)d_in[4];
  const float* initls  = (const float*)d_in[5];
  const float* transg  = (const float*)d_in[6];
  const float* Ag      = (const float*)d_in[7];
  const float* dynoff  = (const float*)d_in[8];
  const float* dynls   = (const float*)d_in[9];
  const float* Cg      = (const float*)d_in[10];
  const float* emoff   = (const float*)d_in[11];
  const float* emls    = (const float*)d_in[12];
  float* out = (float*)d_out;

  hipMemsetAsync(d_out, 0, BB * sizeof(float), stream);

  // 1024 blocks x 400 items each == exactly B*T; uniform 4 blocks/CU
  // (VGPR 65..128 residency class), single round, no tail
  slds_lp_kernel<<<1024, 256, 0, stream>>>(dsts, zg, obsg, initlg, initloc,
                                           initls, transg, Ag, dynoff, dynls,
                                           Cg, emoff, emls, out);
}